// Round 2
// baseline (153.986 us; speedup 1.0000x reference)
//
#include <hip/hip_runtime.h>

// Problem constants (from reference)
#define DIM   128
#define KNEG  20

// Numerically stable log(sigmoid(x)) = -softplus(-x)
__device__ __forceinline__ float log_sigmoid(float x) {
    float ax = fabsf(x);
    float t = log1pf(__expf(-ax));
    return (x >= 0.0f) ? -t : (x - t);
}

// Tiny kernel to zero the scalar accumulator. Replaces last round's
// hipMemsetAsync(d_out) — the only novel host API call in the round that
// killed the container twice; a plain kernel launch is the one path the
// harness graph-capture is guaranteed to support. Stream order puts this
// before all atomicAdds from the main kernel.
__global__ void zero_out_kernel(float* __restrict__ out) {
    out[0] = 0.0f;
}

// One batch element per 32-lane HALF-wave (2 elements per wave).
// A 128-float row = 512 B = 32 lanes x float4, so each half-wave covers a
// full row per load instruction; the two halves fetch rows of two different
// elements in the same instruction — zero wasted lanes, zero wasted rows.
//
// NO workspace, NO finalize kernel. Each block atomicAdds its pre-scaled
// contribution -blocksum/batch_size directly into out[0]. Purpose: test
// whether the 256 MiB fillBufferAligned poison dispatches (3 x ~40.5 us =
// ~90% of the timed window at 133.7 us) are conditional on d_ws usage.
__global__ __launch_bounds__(256) void skipgram_loss_kernel(
    const float* __restrict__ u_emb,   // [VOCAB, 128] float32
    const float* __restrict__ v_emb,   // [VOCAB, 128] float32
    const int* __restrict__ u_pos,     // [B] int32
    const int* __restrict__ v_pos,     // [B] int32
    const int* __restrict__ v_neg,     // [B, 20] int32
    const int* __restrict__ batch_size,// [1] int32
    float* __restrict__ out,           // [1] float32, pre-zeroed
    int B_total)
{
    const int lane  = threadIdx.x & 63;
    const int wib   = threadIdx.x >> 6;         // wave in block (0..3)
    const int half  = lane >> 5;                // which half-wave (0/1)
    const int l32   = lane & 31;
    const int col   = l32 * 4;                  // float4 column within a row
    const int b     = (blockIdx.x * 4 + wib) * 2 + half;  // element for this half
    const int hbase = half << 5;

    float p = 0.0f, nd = 0.0f;
    const bool valid = (b < B_total);

    // Gather the 22 indices of this half's element with one load instruction:
    //   l32 0     -> v_pos[b]
    //   l32 1..20 -> v_neg[b*20 + l32-1]
    //   l32 21    -> u_pos[b]
    int myidx = 0;
    if (valid) {
        if (l32 == 0)            myidx = v_pos[b];
        else if (l32 <= KNEG)    myidx = v_neg[b * KNEG + l32 - 1];
        else if (l32 == 21)      myidx = u_pos[b];
    }

    if (valid) {
        const int ui = __shfl(myidx, hbase + 21, 64);
        const float4 U = *(const float4*)(u_emb + (size_t)ui * DIM + col);

        float4 ns = make_float4(0.f, 0.f, 0.f, 0.f);
        #pragma unroll
        for (int r = 0; r <= KNEG; ++r) {       // r=0: positive, r=1..20: negatives
            const int idx = __shfl(myidx, hbase + r, 64);
            const float4 row = *(const float4*)(v_emb + (size_t)idx * DIM + col);
            if (r == 0) {
                p = U.x * row.x + U.y * row.y + U.z * row.z + U.w * row.w;
            } else {
                ns.x += row.x; ns.y += row.y; ns.z += row.z; ns.w += row.w;
            }
        }
        nd = U.x * ns.x + U.y * ns.y + U.z * ns.z + U.w * ns.w;
    }

    // Reduce within each 32-lane half (offsets < 32 stay inside the half)
    #pragma unroll
    for (int off = 16; off > 0; off >>= 1) {
        p  += __shfl_xor(p,  off, 64);
        nd += __shfl_xor(nd, off, 64);
    }

    float local = 0.0f;
    if (l32 == 0 && valid) {
        local = log_sigmoid(p) + log_sigmoid(-nd);
    }
    // Combine the two halves: lane0 += lane32's value
    local += __shfl_xor(local, 32, 64);

    // Block reduce (4 waves) -> one device-scope atomic per block
    __shared__ float sbuf[4];
    if (lane == 0) sbuf[wib] = local;
    __syncthreads();
    if (threadIdx.x == 0) {
        const float bsum = sbuf[0] + sbuf[1] + sbuf[2] + sbuf[3];
        // Pre-scale: out accumulates -sum(loss)/batch_size directly.
        atomicAdd(out, -bsum / (float)batch_size[0]);
    }
}

extern "C" void kernel_launch(void* const* d_in, const int* in_sizes, int n_in,
                              void* d_out, int out_size, void* d_ws, size_t ws_size,
                              hipStream_t stream) {
    const float* u_emb = (const float*)d_in[0];
    const float* v_emb = (const float*)d_in[1];
    const int* u_pos = (const int*)d_in[2];
    const int* v_pos = (const int*)d_in[3];
    const int* v_neg = (const int*)d_in[4];
    const int* bsz   = (const int*)d_in[5];

    const int B_total = in_sizes[2];           // 16384
    // 2 elements per wave, 4 waves per block -> 8 elements per block.
    const int blocks = (B_total + 7) / 8;      // 2048 blocks = 8192 waves = 32/CU, single pass

    // Zero the scalar accumulator via kernel (no memset API during capture).
    // Workspace d_ws is intentionally untouched.
    zero_out_kernel<<<1, 1, 0, stream>>>((float*)d_out);

    skipgram_loss_kernel<<<blocks, 256, 0, stream>>>(
        u_emb, v_emb, u_pos, v_pos, v_neg, bsz, (float*)d_out, B_total);
}

// Round 3
// 132.796 us; speedup vs baseline: 1.1596x; 1.1596x over previous
//
#include <hip/hip_runtime.h>

// Problem constants (from reference)
#define DIM   128
#define KNEG  20

// Numerically stable log(sigmoid(x)) = -softplus(-x)
__device__ __forceinline__ float log_sigmoid(float x) {
    float ax = fabsf(x);
    float t = log1pf(__expf(-ax));
    return (x >= 0.0f) ? -t : (x - t);
}

// One batch element per 32-lane HALF-wave (2 elements per wave).
// A 128-float row = 512 B = 32 lanes x float4, so each half-wave covers a
// full row per load instruction.
//
// Round-3 change (vs the 133.7 us round-0 baseline): the gather loop is
// restructured for memory-level parallelism. Round-2 profiling showed the
// kernel at 50 us / 1.7 TB/s / VGPR=20 — latency-bound, with the compiler
// holding only ~2 row-loads in flight. Here the 21 v-rows are fetched in
// explicitly double-buffered batches of 4 (plus U and the positive row
// issued up front): 8-10 rows (4-5 KB) in flight per half-wave in steady
// state, ~55 VGPRs — still <=64, so full 32 waves/CU occupancy is kept.
// Workspace/finalize structure is restored exactly from round 0 (the
// no-ws atomic experiment regressed total 133.7 -> 154.0; fills are a
// fixed harness cost, not conditional on d_ws usage).
__global__ __launch_bounds__(256) void skipgram_loss_kernel(
    const float* __restrict__ u_emb,   // [VOCAB, 128] float32
    const float* __restrict__ v_emb,   // [VOCAB, 128] float32
    const int* __restrict__ u_pos,     // [B] int32
    const int* __restrict__ v_pos,     // [B] int32
    const int* __restrict__ v_neg,     // [B, 20] int32
    float* __restrict__ partials,      // [gridDim.x] per-block partial sums
    int B_total)
{
    const int lane  = threadIdx.x & 63;
    const int wib   = threadIdx.x >> 6;         // wave in block (0..3)
    const int half  = lane >> 5;                // which half-wave (0/1)
    const int l32   = lane & 31;
    const int col   = l32 * 4;                  // float4 column within a row
    const int b     = (blockIdx.x * 4 + wib) * 2 + half;  // element for this half
    const int hbase = half << 5;

    float p = 0.0f, nd = 0.0f;
    const bool valid = (b < B_total);

    // Gather the 22 indices of this half's element with one load instruction:
    //   l32 0     -> v_pos[b]
    //   l32 1..20 -> v_neg[b*20 + l32-1]
    //   l32 21    -> u_pos[b]
    int myidx = 0;
    if (valid) {
        if (l32 == 0)            myidx = v_pos[b];
        else if (l32 <= KNEG)    myidx = v_neg[b * KNEG + l32 - 1];
        else if (l32 == 21)      myidx = u_pos[b];
    }

    if (valid) {
        const float* vcol = v_emb + col;

        // Issue U and the positive row first (oldest in the vmcnt queue, so
        // consuming them leaves the negative batches in flight).
        const int ui = __shfl(myidx, hbase + 21, 64);
        const float4 U = *(const float4*)(u_emb + (size_t)ui * DIM + col);
        const int pi = __shfl(myidx, hbase + 0, 64);
        const float4 P = *(const float4*)(vcol + (size_t)pi * DIM);

        // Double-buffered negative-row batches: A <- negs 1..4, B <- negs 5..8
        float4 A[4], Bv[4];
        #pragma unroll
        for (int i = 0; i < 4; ++i) {
            const int idx = __shfl(myidx, hbase + 1 + i, 64);
            A[i] = *(const float4*)(vcol + (size_t)idx * DIM);
        }
        #pragma unroll
        for (int i = 0; i < 4; ++i) {
            const int idx = __shfl(myidx, hbase + 5 + i, 64);
            Bv[i] = *(const float4*)(vcol + (size_t)idx * DIM);
        }

        // Positive score while 8 negative rows are in flight.
        p = U.x * P.x + U.y * P.y + U.z * P.z + U.w * P.w;

        float4 ns = make_float4(0.f, 0.f, 0.f, 0.f);

        // consume A (negs 1..4), refill A <- negs 9..12
        #pragma unroll
        for (int i = 0; i < 4; ++i) {
            ns.x += A[i].x; ns.y += A[i].y; ns.z += A[i].z; ns.w += A[i].w;
        }
        #pragma unroll
        for (int i = 0; i < 4; ++i) {
            const int idx = __shfl(myidx, hbase + 9 + i, 64);
            A[i] = *(const float4*)(vcol + (size_t)idx * DIM);
        }
        // consume B (negs 5..8), refill B <- negs 13..16
        #pragma unroll
        for (int i = 0; i < 4; ++i) {
            ns.x += Bv[i].x; ns.y += Bv[i].y; ns.z += Bv[i].z; ns.w += Bv[i].w;
        }
        #pragma unroll
        for (int i = 0; i < 4; ++i) {
            const int idx = __shfl(myidx, hbase + 13 + i, 64);
            Bv[i] = *(const float4*)(vcol + (size_t)idx * DIM);
        }
        // consume A (negs 9..12), refill A <- negs 17..20
        #pragma unroll
        for (int i = 0; i < 4; ++i) {
            ns.x += A[i].x; ns.y += A[i].y; ns.z += A[i].z; ns.w += A[i].w;
        }
        #pragma unroll
        for (int i = 0; i < 4; ++i) {
            const int idx = __shfl(myidx, hbase + 17 + i, 64);
            A[i] = *(const float4*)(vcol + (size_t)idx * DIM);
        }
        // consume B (negs 13..16), then the final A (negs 17..20)
        #pragma unroll
        for (int i = 0; i < 4; ++i) {
            ns.x += Bv[i].x; ns.y += Bv[i].y; ns.z += Bv[i].z; ns.w += Bv[i].w;
        }
        #pragma unroll
        for (int i = 0; i < 4; ++i) {
            ns.x += A[i].x; ns.y += A[i].y; ns.z += A[i].z; ns.w += A[i].w;
        }

        nd = U.x * ns.x + U.y * ns.y + U.z * ns.z + U.w * ns.w;
    }

    // Reduce within each 32-lane half (offsets < 32 stay inside the half)
    #pragma unroll
    for (int off = 16; off > 0; off >>= 1) {
        p  += __shfl_xor(p,  off, 64);
        nd += __shfl_xor(nd, off, 64);
    }

    float local = 0.0f;
    if (l32 == 0 && valid) {
        local = log_sigmoid(p) + log_sigmoid(-nd);
    }
    // Combine the two halves: lane0 += lane32's value
    local += __shfl_xor(local, 32, 64);

    // Block reduce (4 waves) -> plain store of this block's partial
    __shared__ float sbuf[4];
    if (lane == 0) sbuf[wib] = local;
    __syncthreads();
    if (threadIdx.x == 0) {
        partials[blockIdx.x] = sbuf[0] + sbuf[1] + sbuf[2] + sbuf[3];
    }
}

__global__ __launch_bounds__(256) void finalize_kernel(
    const float* __restrict__ partials, int n,
    const int* __restrict__ batch_size,
    float* __restrict__ out)
{
    const int lane = threadIdx.x & 63;
    const int wib  = threadIdx.x >> 6;

    float s = 0.0f;
    for (int i = threadIdx.x; i < n; i += 256) s += partials[i];

    #pragma unroll
    for (int off = 32; off > 0; off >>= 1) s += __shfl_xor(s, off, 64);

    __shared__ float sbuf[4];
    if (lane == 0) sbuf[wib] = s;
    __syncthreads();
    if (threadIdx.x == 0) {
        float total = sbuf[0] + sbuf[1] + sbuf[2] + sbuf[3];
        out[0] = -total / (float)batch_size[0];   // output is float32
    }
}

extern "C" void kernel_launch(void* const* d_in, const int* in_sizes, int n_in,
                              void* d_out, int out_size, void* d_ws, size_t ws_size,
                              hipStream_t stream) {
    const float* u_emb = (const float*)d_in[0];
    const float* v_emb = (const float*)d_in[1];
    const int* u_pos = (const int*)d_in[2];
    const int* v_pos = (const int*)d_in[3];
    const int* v_neg = (const int*)d_in[4];
    const int* bsz   = (const int*)d_in[5];

    const int B_total = in_sizes[2];           // 16384
    // 2 elements per wave, 4 waves per block -> 8 elements per block.
    const int blocks = (B_total + 7) / 8;      // 2048 blocks = 8192 waves = 32/CU, single pass

    float* partials = (float*)d_ws;

    skipgram_loss_kernel<<<blocks, 256, 0, stream>>>(
        u_emb, v_emb, u_pos, v_pos, v_neg, partials, B_total);

    finalize_kernel<<<1, 256, 0, stream>>>(partials, blocks, bsz, (float*)d_out);
}